// Round 5
// baseline (14772.528 us; speedup 1.0000x reference)
//
#include <hip/hip_runtime.h>
#include <stdint.h>

#define Tn 100
#define Dn 51
#define Hn 128
#define G4 512     // 4*H
#define BR 8       // batch rows per workgroup
#define NWG 256    // workgroups (2048 / 8)
#define NTH 256    // threads per workgroup (4 waves)

typedef unsigned int uint32;

__device__ __forceinline__ float rcp_(float x){ return __builtin_amdgcn_rcpf(x); }
__device__ __forceinline__ float sigm(float x){ return rcp_(1.f + __expf(-x)); }
// tanh(x) = 1 - 2/(exp(2x)+1): stable at both tails (+inf -> 1, -inf -> -1)
__device__ __forceinline__ float tanh_(float x){ return 1.f - 2.f*rcp_(1.f + __expf(2.f*x)); }

struct WP {
  const float* W[6];   // [4H, din]  enc0..2, dec0..2 (fp32)
  const float* U[6];   // [4H, H]
  const float* Bb[6];  // [4H]
  const float* fW;     // [D, H]
  const float* fb;     // [D]
};

// Build transposed+concatenated weights in workspace (fp32):
//   wc[l][k][c] = k<din ? Wih[c][k] : (k<din+H ? U[c][k-din] : 0), [256][512]/layer
//   bias[l][c] ; fwt[k][d] = fW[d][k] (d padded 51->64) ; fbw[d]
#define PREP_TOTAL (6*131072 + 6*512 + 8192 + 64)
__global__ void prep_kernel(WP p, float* __restrict__ wc, float* __restrict__ bias,
                            float* __restrict__ fwt, float* __restrict__ fbw)
{
  int gid = blockIdx.x*NTH + threadIdx.x;
  if (gid >= PREP_TOTAL) return;
  if (gid < 6*131072){
    int l = gid >> 17;
    int e = gid & 131071;
    int k = e >> 9;
    int c = e & 511;
    int din = (l % 3 == 0) ? Dn : Hn;
    float v = 0.f;
    if (k < din)           v = p.W[l][(size_t)c*din + k];
    else if (k < din + Hn) v = p.U[l][(size_t)c*Hn + (k - din)];
    wc[gid] = v;
  } else if (gid < 6*131072 + 6*512){
    int i = gid - 6*131072;
    bias[i] = p.Bb[i>>9][i & 511];
  } else if (gid < 6*131072 + 6*512 + 8192){
    int i = gid - (6*131072 + 6*512);   // < 8192
    int k = i >> 6, d = i & 63;
    fwt[i] = (d < Dn) ? p.fW[(size_t)d*Hn + k] : 0.f;
  } else {
    int d = gid - (6*131072 + 6*512 + 8192);  // < 64
    fbw[d] = (d < Dn) ? p.fb[d] : 0.f;
  }
}

// gates[r][c] = bias[c] + sum_k xh_t[k][r] * wc[k][c]
// col-split: wave w owns cols [w*128, w*128+128), 2 cols/lane, 8 rows/thread.
template<int KK>
__device__ __forceinline__ void gemm_gates(const float* __restrict__ wcl,
                                           const float* __restrict__ bl,
                                           const float* __restrict__ xh,
                                           float* __restrict__ gates, int tid)
{
  const int wave = tid >> 6, lane = tid & 63;
  const int c0 = wave*128 + lane*2;
  float accx[BR], accy[BR];
  #pragma unroll
  for (int r=0;r<BR;r++){ accx[r]=0.f; accy[r]=0.f; }
  const float* wp = wcl + c0;
  #pragma unroll 8
  for (int k=0;k<KK;k++){
    const float2 w = *(const float2*)(wp + (size_t)k*G4); // 2 cols, coalesced
    float w0 = w.x, w1 = w.y;
    const float4 xa = *(const float4*)(xh + k*8);         // broadcast rows 0..3
    const float4 xb = *(const float4*)(xh + k*8 + 4);     // rows 4..7
    accx[0] += xa.x*w0; accy[0] += xa.x*w1;
    accx[1] += xa.y*w0; accy[1] += xa.y*w1;
    accx[2] += xa.z*w0; accy[2] += xa.z*w1;
    accx[3] += xa.w*w0; accy[3] += xa.w*w1;
    accx[4] += xb.x*w0; accy[4] += xb.x*w1;
    accx[5] += xb.y*w0; accy[5] += xb.y*w1;
    accx[6] += xb.z*w0; accy[6] += xb.z*w1;
    accx[7] += xb.w*w0; accy[7] += xb.w*w1;
  }
  float b0 = bl[c0], b1 = bl[c0+1];
  #pragma unroll
  for (int r=0;r<BR;r++){
    gates[r*G4 + c0]     = accx[r] + b0;
    gates[r*G4 + c0 + 1] = accy[r] + b1;
  }
}

__device__ __forceinline__ void activate(const float* __restrict__ gates,
                                         float* __restrict__ h, float* __restrict__ c, int tid)
{
  #pragma unroll
  for (int i=0;i<4;i++){
    int e = tid + i*NTH;            // 0..1023 = 8 rows x 128
    int r = e >> 7, j = e & 127;
    const float* g = gates + r*G4;
    float ig = sigm(g[j]);
    float fg = sigm(g[j + Hn]);
    float gg = tanh_(g[j + 2*Hn]);
    float og = sigm(g[j + 3*Hn]);
    int hi = r*Hn + j;
    float cn = fg*c[hi] + ig*gg;
    c[hi] = cn;
    h[hi] = og*tanh_(cn);
  }
}

// builders: write xh_t[k][r], zero-padded to KK
__device__ __forceinline__ void build_src(float* __restrict__ xh, const float* __restrict__ src,
                                          long b0, int t, const float* __restrict__ h0, int tid)
{
  #pragma unroll
  for (int r=0;r<BR;r++){
    const float* s = src + ((size_t)(b0+r)*Tn + t)*Dn;
    int k = tid;
    if (k < 192){
      float v;
      if (k < Dn) v = s[k];
      else if (k < Dn + Hn) v = h0[r*Hn + (k - Dn)];
      else v = 0.f;
      xh[k*8 + r] = v;
    }
  }
}

__device__ __forceinline__ void build_pred(float* __restrict__ xh, const float* __restrict__ pred,
                                           const float* __restrict__ h0, int tid)
{
  #pragma unroll
  for (int r=0;r<BR;r++){
    int k = tid;
    if (k < 192){
      float v;
      if (k < Dn) v = pred[r*64 + k];
      else if (k < Dn + Hn) v = h0[r*Hn + (k - Dn)];
      else v = 0.f;
      xh[k*8 + r] = v;
    }
  }
}

__device__ __forceinline__ void build_mid(float* __restrict__ xh, const float* __restrict__ hlow,
                                          const float* __restrict__ hl, int tid)
{
  #pragma unroll
  for (int r=0;r<BR;r++){
    int k = tid;   // 0..255
    float v = (k < Hn) ? hlow[r*Hn + k] : hl[r*Hn + (k - Hn)];
    xh[k*8 + r] = v;
  }
}

// OUTPUT IS FP32 (reference returns float32; harness reads float32).
__device__ __forceinline__ void proj_out(const float* __restrict__ h2, const float* __restrict__ fwt,
                                         const float* __restrict__ fbw, float* __restrict__ pred,
                                         float* __restrict__ out, long b0, int t, int tid)
{
  #pragma unroll
  for (int it=0; it<2; it++){
    int e = tid + it*NTH;           // 0..511 = 8 rows x 64
    int r = e >> 6, d = e & 63;
    const float* h = h2 + r*Hn;
    float acc = 0.f;
    #pragma unroll 8
    for (int k=0;k<Hn;k++) acc += h[k] * fwt[k*64 + d];
    if (d < Dn){
      float pv = acc + fbw[d];
      pred[r*64 + d] = pv;
      out[((size_t)(b0+r)*Tn + (Tn-1-t))*Dn + d] = pv;   // fp32 store
    }
  }
}

__global__ __launch_bounds__(NTH) void lstm_kernel(
    const float* __restrict__ src, const float* __restrict__ wc,
    const float* __restrict__ bias, const float* __restrict__ fwt,
    const float* __restrict__ fbw, float* __restrict__ out)
{
  __shared__ __align__(16) float xh[256*BR];      // 8 KB  transposed [k][r]
  __shared__ __align__(16) float gates[BR*G4];    // 16 KB
  __shared__ __align__(16) float hS[3*BR*Hn];     // 12 KB
  __shared__ __align__(16) float cS[3*BR*Hn];     // 12 KB
  __shared__ __align__(16) float pred[BR*64];     // 2 KB

  const int tid = threadIdx.x;
  const long b0 = (long)blockIdx.x * BR;

  for (int i=tid; i<3*BR*Hn; i+=NTH){ hS[i]=0.f; cS[i]=0.f; }
  __syncthreads();

  // ---------------- encoder ----------------
  for (int t=0;t<Tn;t++){
    build_src(xh, src, b0, t, hS, tid);
    __syncthreads();
    gemm_gates<192>(wc + 0*131072, bias + 0*G4, xh, gates, tid);
    __syncthreads();
    activate(gates, hS, cS, tid);
    __syncthreads();

    build_mid(xh, hS, hS + BR*Hn, tid);
    __syncthreads();
    gemm_gates<256>(wc + 1*131072, bias + 1*G4, xh, gates, tid);
    __syncthreads();
    activate(gates, hS + BR*Hn, cS + BR*Hn, tid);
    __syncthreads();

    build_mid(xh, hS + BR*Hn, hS + 2*BR*Hn, tid);
    __syncthreads();
    gemm_gates<256>(wc + 2*131072, bias + 2*G4, xh, gates, tid);
    __syncthreads();
    activate(gates, hS + 2*BR*Hn, cS + 2*BR*Hn, tid);
    __syncthreads();
  }

  // ---------------- decoder ----------------
  pred[tid] = 0.f; pred[tid + NTH] = 0.f;   // x0 = zeros
  __syncthreads();

  for (int t=0;t<Tn;t++){
    build_pred(xh, pred, hS, tid);
    __syncthreads();
    gemm_gates<192>(wc + 3*131072, bias + 3*G4, xh, gates, tid);
    __syncthreads();
    activate(gates, hS, cS, tid);
    __syncthreads();

    build_mid(xh, hS, hS + BR*Hn, tid);
    __syncthreads();
    gemm_gates<256>(wc + 4*131072, bias + 4*G4, xh, gates, tid);
    __syncthreads();
    activate(gates, hS + BR*Hn, cS + BR*Hn, tid);
    __syncthreads();

    build_mid(xh, hS + BR*Hn, hS + 2*BR*Hn, tid);
    __syncthreads();
    gemm_gates<256>(wc + 5*131072, bias + 5*G4, xh, gates, tid);
    __syncthreads();
    activate(gates, hS + 2*BR*Hn, cS + 2*BR*Hn, tid);
    __syncthreads();

    proj_out(hS + 2*BR*Hn, fwt, fbw, pred, out, b0, t, tid);
    __syncthreads();
  }
}

extern "C" void kernel_launch(void* const* d_in, const int* in_sizes, int n_in,
                              void* d_out, int out_size, void* d_ws, size_t ws_size,
                              hipStream_t stream)
{
  (void)in_sizes; (void)n_in; (void)out_size; (void)ws_size;
  const float* src = (const float*)d_in[0];
  WP p;
  for (int l=0;l<3;l++){
    p.W[l]    = (const float*)d_in[1  + 3*l];
    p.U[l]    = (const float*)d_in[2  + 3*l];
    p.Bb[l]   = (const float*)d_in[3  + 3*l];
    p.W[3+l]  = (const float*)d_in[10 + 3*l];
    p.U[3+l]  = (const float*)d_in[11 + 3*l];
    p.Bb[3+l] = (const float*)d_in[12 + 3*l];
  }
  p.fW = (const float*)d_in[19];
  p.fb = (const float*)d_in[20];

  // ws layout (fp32): wc[786432] | bias[3072] | fwt[8192] | fbw[64]
  float* wc   = (float*)d_ws;
  float* bias = wc + 6*131072;
  float* fwt  = bias + 6*512;
  float* fbw  = fwt + 8192;

  prep_kernel<<<(PREP_TOTAL + NTH - 1)/NTH, NTH, 0, stream>>>(p, wc, bias, fwt, fbw);
  lstm_kernel<<<NWG, NTH, 0, stream>>>(src, wc, bias, fwt, fbw, (float*)d_out);
}

// Round 6
// 7845.760 us; speedup vs baseline: 1.8829x; 1.8829x over previous
//
#include <hip/hip_runtime.h>
#include <stdint.h>

#define Tn 100
#define Dn 51
#define Hn 128
#define G4 512     // 4*H
#define BR 8       // batch rows per workgroup
#define NWG 256    // workgroups (2048 / 8)
#define NTH 512    // threads per workgroup (8 waves: col-group x K-half)

typedef unsigned int uint32;

__device__ __forceinline__ float rcp_(float x){ return __builtin_amdgcn_rcpf(x); }
__device__ __forceinline__ float sigm(float x){ return rcp_(1.f + __expf(-x)); }
// tanh(x) = 1 - 2/(exp(2x)+1): stable at both tails (+inf -> 1, -inf -> -1)
__device__ __forceinline__ float tanh_(float x){ return 1.f - 2.f*rcp_(1.f + __expf(2.f*x)); }

struct WP {
  const float* W[6];   // [4H, din]  enc0..2, dec0..2 (fp32)
  const float* U[6];   // [4H, H]
  const float* Bb[6];  // [4H]
  const float* fW;     // [D, H]
  const float* fb;     // [D]
};

// Build transposed+concatenated weights in workspace (fp32):
//   wc[l][k][c] = k<din ? Wih[c][k] : (k<din+H ? U[c][k-din] : 0), [256][512]/layer
//   bias[l][c] ; fwt[k][d] = fW[d][k] (d padded 51->64) ; fbw[d]
#define PREP_TOTAL (6*131072 + 6*512 + 8192 + 64)
__global__ void prep_kernel(WP p, float* __restrict__ wc, float* __restrict__ bias,
                            float* __restrict__ fwt, float* __restrict__ fbw)
{
  int gid = blockIdx.x*256 + threadIdx.x;
  if (gid >= PREP_TOTAL) return;
  if (gid < 6*131072){
    int l = gid >> 17;
    int e = gid & 131071;
    int k = e >> 9;
    int c = e & 511;
    int din = (l % 3 == 0) ? Dn : Hn;
    float v = 0.f;
    if (k < din)           v = p.W[l][(size_t)c*din + k];
    else if (k < din + Hn) v = p.U[l][(size_t)c*Hn + (k - din)];
    wc[gid] = v;
  } else if (gid < 6*131072 + 6*512){
    int i = gid - 6*131072;
    bias[i] = p.Bb[i>>9][i & 511];
  } else if (gid < 6*131072 + 6*512 + 8192){
    int i = gid - (6*131072 + 6*512);   // < 8192
    int k = i >> 6, d = i & 63;
    fwt[i] = (d < Dn) ? p.fW[(size_t)d*Hn + k] : 0.f;
  } else {
    int d = gid - (6*131072 + 6*512 + 8192);  // < 64
    fbw[d] = (d < Dn) ? p.fb[d] : 0.f;
  }
}

// gates[r][c] = bias[c] + sum_k xh_t[k][r] * wc[k][c], K-split across wave halves:
// wave w (0..7): col-group = w&3 (128 cols, 2/lane), K-half = w>>2.
// Waves 0-3 write gatesA (with bias), waves 4-7 write gatesB (raw partial).
template<int KK>
__device__ __forceinline__ void gemm_gates(const float* __restrict__ wcl,
                                           const float* __restrict__ bl,
                                           const float* __restrict__ xh,
                                           float* __restrict__ gatesA,
                                           float* __restrict__ gatesB, int tid)
{
  const int wave = tid >> 6, lane = tid & 63;
  const int cg = wave & 3, kh = wave >> 2;
  const int c0 = cg*128 + lane*2;
  const int k0 = kh*(KK/2), k1 = k0 + KK/2;
  float accx[BR], accy[BR];
  #pragma unroll
  for (int r=0;r<BR;r++){ accx[r]=0.f; accy[r]=0.f; }
  const float* wp = wcl + c0;
  #pragma unroll 8
  for (int k=k0;k<k1;k++){
    const float2 w = *(const float2*)(wp + (size_t)k*G4); // 2 cols, coalesced
    float w0 = w.x, w1 = w.y;
    const float4 xa = *(const float4*)(xh + k*8);         // broadcast rows 0..3
    const float4 xb = *(const float4*)(xh + k*8 + 4);     // rows 4..7
    accx[0] += xa.x*w0; accy[0] += xa.x*w1;
    accx[1] += xa.y*w0; accy[1] += xa.y*w1;
    accx[2] += xa.z*w0; accy[2] += xa.z*w1;
    accx[3] += xa.w*w0; accy[3] += xa.w*w1;
    accx[4] += xb.x*w0; accy[4] += xb.x*w1;
    accx[5] += xb.y*w0; accy[5] += xb.y*w1;
    accx[6] += xb.z*w0; accy[6] += xb.z*w1;
    accx[7] += xb.w*w0; accy[7] += xb.w*w1;
  }
  if (kh == 0){
    float b0 = bl[c0], b1 = bl[c0+1];
    #pragma unroll
    for (int r=0;r<BR;r++){
      gatesA[r*G4 + c0]     = accx[r] + b0;
      gatesA[r*G4 + c0 + 1] = accy[r] + b1;
    }
  } else {
    #pragma unroll
    for (int r=0;r<BR;r++){
      gatesB[r*G4 + c0]     = accx[r];
      gatesB[r*G4 + c0 + 1] = accy[r];
    }
  }
}

__device__ __forceinline__ void activate(const float* __restrict__ gA,
                                         const float* __restrict__ gB,
                                         float* __restrict__ h, float* __restrict__ c, int tid)
{
  #pragma unroll
  for (int i=0;i<2;i++){
    int e = tid + i*NTH;            // 0..1023 = 8 rows x 128
    int r = e >> 7, j = e & 127;
    const float* ga = gA + r*G4;
    const float* gb = gB + r*G4;
    float ig = sigm(ga[j]          + gb[j]);
    float fg = sigm(ga[j + Hn]     + gb[j + Hn]);
    float gg = tanh_(ga[j + 2*Hn]  + gb[j + 2*Hn]);
    float og = sigm(ga[j + 3*Hn]   + gb[j + 3*Hn]);
    int hi = r*Hn + j;
    float cn = fg*c[hi] + ig*gg;
    c[hi] = cn;
    h[hi] = og*tanh_(cn);
  }
}

// builders: write xh_t[k][r], zero-padded to KK (threads 0..255 active)
__device__ __forceinline__ void build_src(float* __restrict__ xh, const float* __restrict__ src,
                                          long b0, int t, const float* __restrict__ h0, int tid)
{
  int k = tid;
  if (k < 192){
    #pragma unroll
    for (int r=0;r<BR;r++){
      const float* s = src + ((size_t)(b0+r)*Tn + t)*Dn;
      float v;
      if (k < Dn) v = s[k];
      else if (k < Dn + Hn) v = h0[r*Hn + (k - Dn)];
      else v = 0.f;
      xh[k*8 + r] = v;
    }
  }
}

__device__ __forceinline__ void build_pred(float* __restrict__ xh, const float* __restrict__ pred,
                                           const float* __restrict__ h0, int tid)
{
  int k = tid;
  if (k < 192){
    #pragma unroll
    for (int r=0;r<BR;r++){
      float v;
      if (k < Dn) v = pred[r*64 + k];
      else if (k < Dn + Hn) v = h0[r*Hn + (k - Dn)];
      else v = 0.f;
      xh[k*8 + r] = v;
    }
  }
}

__device__ __forceinline__ void build_mid(float* __restrict__ xh, const float* __restrict__ hlow,
                                          const float* __restrict__ hl, int tid)
{
  int k = tid;
  if (k < 256){
    #pragma unroll
    for (int r=0;r<BR;r++){
      float v = (k < Hn) ? hlow[r*Hn + k] : hl[r*Hn + (k - Hn)];
      xh[k*8 + r] = v;
    }
  }
}

// OUTPUT IS FP32. 512 threads: one (r,d) each over 8 rows x 64 cols.
__device__ __forceinline__ void proj_out(const float* __restrict__ h2, const float* __restrict__ fwt,
                                         const float* __restrict__ fbw, float* __restrict__ pred,
                                         float* __restrict__ out, long b0, int t, int tid)
{
  int r = tid >> 6, d = tid & 63;
  const float* h = h2 + r*Hn;
  float acc = 0.f;
  #pragma unroll 8
  for (int k=0;k<Hn;k++) acc += h[k] * fwt[k*64 + d];
  if (d < Dn){
    float pv = acc + fbw[d];
    pred[r*64 + d] = pv;
    out[((size_t)(b0+r)*Tn + (Tn-1-t))*Dn + d] = pv;   // fp32 store
  }
}

__global__ __launch_bounds__(NTH) void lstm_kernel(
    const float* __restrict__ src, const float* __restrict__ wc,
    const float* __restrict__ bias, const float* __restrict__ fwt,
    const float* __restrict__ fbw, float* __restrict__ out)
{
  __shared__ __align__(16) float xh[256*BR];      // 8 KB  transposed [k][r]
  __shared__ __align__(16) float gatesA[BR*G4];   // 16 KB (K-half 0 + bias)
  __shared__ __align__(16) float gatesB[BR*G4];   // 16 KB (K-half 1)
  __shared__ __align__(16) float hS[3*BR*Hn];     // 12 KB
  __shared__ __align__(16) float cS[3*BR*Hn];     // 12 KB
  __shared__ __align__(16) float pred[BR*64];     // 2 KB

  const int tid = threadIdx.x;
  const long b0 = (long)blockIdx.x * BR;

  for (int i=tid; i<3*BR*Hn; i+=NTH){ hS[i]=0.f; cS[i]=0.f; }
  __syncthreads();

  // ---------------- encoder ----------------
  for (int t=0;t<Tn;t++){
    build_src(xh, src, b0, t, hS, tid);
    __syncthreads();
    gemm_gates<192>(wc + 0*131072, bias + 0*G4, xh, gatesA, gatesB, tid);
    __syncthreads();
    activate(gatesA, gatesB, hS, cS, tid);
    __syncthreads();

    build_mid(xh, hS, hS + BR*Hn, tid);
    __syncthreads();
    gemm_gates<256>(wc + 1*131072, bias + 1*G4, xh, gatesA, gatesB, tid);
    __syncthreads();
    activate(gatesA, gatesB, hS + BR*Hn, cS + BR*Hn, tid);
    __syncthreads();

    build_mid(xh, hS + BR*Hn, hS + 2*BR*Hn, tid);
    __syncthreads();
    gemm_gates<256>(wc + 2*131072, bias + 2*G4, xh, gatesA, gatesB, tid);
    __syncthreads();
    activate(gatesA, gatesB, hS + 2*BR*Hn, cS + 2*BR*Hn, tid);
    __syncthreads();
  }

  // ---------------- decoder ----------------
  pred[tid & 511] = 0.f;   // x0 = zeros (512 elements, 512 threads)
  __syncthreads();

  for (int t=0;t<Tn;t++){
    build_pred(xh, pred, hS, tid);
    __syncthreads();
    gemm_gates<192>(wc + 3*131072, bias + 3*G4, xh, gatesA, gatesB, tid);
    __syncthreads();
    activate(gatesA, gatesB, hS, cS, tid);
    __syncthreads();

    build_mid(xh, hS, hS + BR*Hn, tid);
    __syncthreads();
    gemm_gates<256>(wc + 4*131072, bias + 4*G4, xh, gatesA, gatesB, tid);
    __syncthreads();
    activate(gatesA, gatesB, hS + BR*Hn, cS + BR*Hn, tid);
    __syncthreads();

    build_mid(xh, hS + BR*Hn, hS + 2*BR*Hn, tid);
    __syncthreads();
    gemm_gates<256>(wc + 5*131072, bias + 5*G4, xh, gatesA, gatesB, tid);
    __syncthreads();
    activate(gatesA, gatesB, hS + 2*BR*Hn, cS + 2*BR*Hn, tid);
    __syncthreads();

    proj_out(hS + 2*BR*Hn, fwt, fbw, pred, out, b0, t, tid);
    __syncthreads();
  }
}

extern "C" void kernel_launch(void* const* d_in, const int* in_sizes, int n_in,
                              void* d_out, int out_size, void* d_ws, size_t ws_size,
                              hipStream_t stream)
{
  (void)in_sizes; (void)n_in; (void)out_size; (void)ws_size;
  const float* src = (const float*)d_in[0];
  WP p;
  for (int l=0;l<3;l++){
    p.W[l]    = (const float*)d_in[1  + 3*l];
    p.U[l]    = (const float*)d_in[2  + 3*l];
    p.Bb[l]   = (const float*)d_in[3  + 3*l];
    p.W[3+l]  = (const float*)d_in[10 + 3*l];
    p.U[3+l]  = (const float*)d_in[11 + 3*l];
    p.Bb[3+l] = (const float*)d_in[12 + 3*l];
  }
  p.fW = (const float*)d_in[19];
  p.fb = (const float*)d_in[20];

  // ws layout (fp32): wc[786432] | bias[3072] | fwt[8192] | fbw[64]
  float* wc   = (float*)d_ws;
  float* bias = wc + 6*131072;
  float* fwt  = bias + 6*512;
  float* fbw  = fwt + 8192;

  prep_kernel<<<(PREP_TOTAL + 255)/256, 256, 0, stream>>>(p, wc, bias, fwt, fbw);
  lstm_kernel<<<NWG, NTH, 0, stream>>>(src, wc, bias, fwt, fbw, (float*)d_out);
}

// Round 7
// 6166.933 us; speedup vs baseline: 2.3954x; 1.2722x over previous
//
#include <hip/hip_runtime.h>
#include <stdint.h>

#define Tn 100
#define Dn 51
#define Hn 128
#define G4 512     // 4*H
#define BR 8       // batch rows per workgroup
#define NWG 256    // workgroups (2048 / 8)
#define NTH 1024   // threads per workgroup (16 waves: 4 col-groups x 4 K-quarters)

typedef unsigned int uint32;
typedef float f32x2 __attribute__((ext_vector_type(2)));
typedef float f32x4 __attribute__((ext_vector_type(4)));

__device__ __forceinline__ float rcp_(float x){ return __builtin_amdgcn_rcpf(x); }
__device__ __forceinline__ float sigm(float x){ return rcp_(1.f + __expf(-x)); }
// tanh(x) = 1 - 2/(exp(2x)+1): stable at both tails (+inf -> 1, -inf -> -1)
__device__ __forceinline__ float tanh_(float x){ return 1.f - 2.f*rcp_(1.f + __expf(2.f*x)); }

struct WP {
  const float* W[6];   // [4H, din]  enc0..2, dec0..2 (fp32)
  const float* U[6];   // [4H, H]
  const float* Bb[6];  // [4H]
  const float* fW;     // [D, H]
  const float* fb;     // [D]
};

// Build transposed+concatenated weights in workspace (fp32):
//   wc[l][k][c] = k<din ? Wih[c][k] : (k<din+H ? U[c][k-din] : 0), [256][512]/layer
//   bias[l][c] ; fwt[k][d] = fW[d][k] (d padded 51->64) ; fbw[d]
#define PREP_TOTAL (6*131072 + 6*512 + 8192 + 64)
__global__ void prep_kernel(WP p, float* __restrict__ wc, float* __restrict__ bias,
                            float* __restrict__ fwt, float* __restrict__ fbw)
{
  int gid = blockIdx.x*256 + threadIdx.x;
  if (gid >= PREP_TOTAL) return;
  if (gid < 6*131072){
    int l = gid >> 17;
    int e = gid & 131071;
    int k = e >> 9;
    int c = e & 511;
    int din = (l % 3 == 0) ? Dn : Hn;
    float v = 0.f;
    if (k < din)           v = p.W[l][(size_t)c*din + k];
    else if (k < din + Hn) v = p.U[l][(size_t)c*Hn + (k - din)];
    wc[gid] = v;
  } else if (gid < 6*131072 + 6*512){
    int i = gid - 6*131072;
    bias[i] = p.Bb[i>>9][i & 511];
  } else if (gid < 6*131072 + 6*512 + 8192){
    int i = gid - (6*131072 + 6*512);   // < 8192
    int k = i >> 6, d = i & 63;
    fwt[i] = (d < Dn) ? p.fW[(size_t)d*Hn + k] : 0.f;
  } else {
    int d = gid - (6*131072 + 6*512 + 8192);  // < 64
    fbw[d] = (d < Dn) ? p.fb[d] : 0.f;
  }
}

// gates partial q: gatesP[q][r][c] = (q==0? bias[c]:0) + sum_{k in quarter q} xh[k][r]*wc[k][c]
// wave w (0..15): col-group = w&3 (128 cols, 2/lane as float2 -> v_pk_fma), K-quarter = w>>2.
template<int KK>
__device__ __forceinline__ void gemm_gates(const float* __restrict__ wcl,
                                           const float* __restrict__ bl,
                                           const float* __restrict__ xh,
                                           float* __restrict__ gatesP, int tid)
{
  const int wave = tid >> 6, lane = tid & 63;
  const int cg = wave & 3, kq = wave >> 2;
  const int c0 = cg*128 + lane*2;
  const int k0 = kq*(KK/4), k1 = k0 + KK/4;
  f32x2 acc[BR];
  #pragma unroll
  for (int r=0;r<BR;r++) acc[r] = (f32x2){0.f, 0.f};
  const float* wp = wcl + c0;
  #pragma unroll 8
  for (int k=k0;k<k1;k++){
    const f32x2 w2 = *(const f32x2*)(wp + (size_t)k*G4); // 2 cols, coalesced
    const f32x4 xa = *(const f32x4*)(xh + k*8);          // broadcast rows 0..3
    const f32x4 xb = *(const f32x4*)(xh + k*8 + 4);      // rows 4..7
    acc[0] += w2 * xa.x;   // splat -> v_pk_fma_f32
    acc[1] += w2 * xa.y;
    acc[2] += w2 * xa.z;
    acc[3] += w2 * xa.w;
    acc[4] += w2 * xb.x;
    acc[5] += w2 * xb.y;
    acc[6] += w2 * xb.z;
    acc[7] += w2 * xb.w;
  }
  float* gq = gatesP + kq*(BR*G4);
  if (kq == 0){
    const f32x2 b2 = *(const f32x2*)(bl + c0);
    #pragma unroll
    for (int r=0;r<BR;r++) *(f32x2*)(gq + r*G4 + c0) = acc[r] + b2;
  } else {
    #pragma unroll
    for (int r=0;r<BR;r++) *(f32x2*)(gq + r*G4 + c0) = acc[r];
  }
}

__device__ __forceinline__ void activate(const float* __restrict__ gP,
                                         float* __restrict__ h, float* __restrict__ c, int tid)
{
  int e = tid;                     // 0..1023 = 8 rows x 128
  int r = e >> 7, j = e & 127;
  const float* g0 = gP + 0*(BR*G4) + r*G4;
  const float* g1 = gP + 1*(BR*G4) + r*G4;
  const float* g2 = gP + 2*(BR*G4) + r*G4;
  const float* g3 = gP + 3*(BR*G4) + r*G4;
  float ig = sigm (g0[j]        + g1[j]        + g2[j]        + g3[j]);
  float fg = sigm (g0[j+Hn]     + g1[j+Hn]     + g2[j+Hn]     + g3[j+Hn]);
  float gg = tanh_(g0[j+2*Hn]   + g1[j+2*Hn]   + g2[j+2*Hn]   + g3[j+2*Hn]);
  float og = sigm (g0[j+3*Hn]   + g1[j+3*Hn]   + g2[j+3*Hn]   + g3[j+3*Hn]);
  int hi = r*Hn + j;
  float cn = fg*c[hi] + ig*gg;
  c[hi] = cn;
  h[hi] = og*tanh_(cn);
}

// builders: write xh_t[k][r], zero-padded to KK (threads 0..255 active)
__device__ __forceinline__ void build_src(float* __restrict__ xh, const float* __restrict__ src,
                                          long b0, int t, const float* __restrict__ h0, int tid)
{
  int k = tid;
  if (k < 192){
    #pragma unroll
    for (int r=0;r<BR;r++){
      const float* s = src + ((size_t)(b0+r)*Tn + t)*Dn;
      float v;
      if (k < Dn) v = s[k];
      else if (k < Dn + Hn) v = h0[r*Hn + (k - Dn)];
      else v = 0.f;
      xh[k*8 + r] = v;
    }
  }
}

__device__ __forceinline__ void build_pred(float* __restrict__ xh, const float* __restrict__ pred,
                                           const float* __restrict__ h0, int tid)
{
  int k = tid;
  if (k < 192){
    #pragma unroll
    for (int r=0;r<BR;r++){
      float v;
      if (k < Dn) v = pred[r*64 + k];
      else if (k < Dn + Hn) v = h0[r*Hn + (k - Dn)];
      else v = 0.f;
      xh[k*8 + r] = v;
    }
  }
}

__device__ __forceinline__ void build_mid(float* __restrict__ xh, const float* __restrict__ hlow,
                                          const float* __restrict__ hl, int tid)
{
  int k = tid;
  if (k < 256){
    #pragma unroll
    for (int r=0;r<BR;r++){
      float v = (k < Hn) ? hlow[r*Hn + k] : hl[r*Hn + (k - Hn)];
      xh[k*8 + r] = v;
    }
  }
}

// OUTPUT IS FP32. Work items: 8 rows x 64 cols = 512 (threads >=512 idle).
__device__ __forceinline__ void proj_out(const float* __restrict__ h2, const float* __restrict__ fwt,
                                         const float* __restrict__ fbw, float* __restrict__ pred,
                                         float* __restrict__ out, long b0, int t, int tid)
{
  if (tid < 512){
    int r = tid >> 6, d = tid & 63;
    const float* h = h2 + r*Hn;
    float acc = 0.f;
    #pragma unroll 8
    for (int k=0;k<Hn;k++) acc += h[k] * fwt[k*64 + d];
    if (d < Dn){
      float pv = acc + fbw[d];
      pred[r*64 + d] = pv;
      out[((size_t)(b0+r)*Tn + (Tn-1-t))*Dn + d] = pv;   // fp32 store
    }
  }
}

__global__ __launch_bounds__(NTH) void lstm_kernel(
    const float* __restrict__ src, const float* __restrict__ wc,
    const float* __restrict__ bias, const float* __restrict__ fwt,
    const float* __restrict__ fbw, float* __restrict__ out)
{
  __shared__ __align__(16) float xh[256*BR];      // 8 KB  transposed [k][r]
  __shared__ __align__(16) float gatesP[4*BR*G4]; // 64 KB (4 K-quarter partials)
  __shared__ __align__(16) float hS[3*BR*Hn];     // 12 KB
  __shared__ __align__(16) float cS[3*BR*Hn];     // 12 KB
  __shared__ __align__(16) float pred[BR*64];     // 2 KB

  const int tid = threadIdx.x;
  const long b0 = (long)blockIdx.x * BR;

  for (int i=tid; i<3*BR*Hn; i+=NTH){ hS[i]=0.f; cS[i]=0.f; }
  __syncthreads();

  // ---------------- encoder ----------------
  for (int t=0;t<Tn;t++){
    build_src(xh, src, b0, t, hS, tid);
    __syncthreads();
    gemm_gates<192>(wc + 0*131072, bias + 0*G4, xh, gatesP, tid);
    __syncthreads();
    activate(gatesP, hS, cS, tid);
    __syncthreads();

    build_mid(xh, hS, hS + BR*Hn, tid);
    __syncthreads();
    gemm_gates<256>(wc + 1*131072, bias + 1*G4, xh, gatesP, tid);
    __syncthreads();
    activate(gatesP, hS + BR*Hn, cS + BR*Hn, tid);
    __syncthreads();

    build_mid(xh, hS + BR*Hn, hS + 2*BR*Hn, tid);
    __syncthreads();
    gemm_gates<256>(wc + 2*131072, bias + 2*G4, xh, gatesP, tid);
    __syncthreads();
    activate(gatesP, hS + 2*BR*Hn, cS + 2*BR*Hn, tid);
    __syncthreads();
  }

  // ---------------- decoder ----------------
  if (tid < 512) pred[tid] = 0.f;   // x0 = zeros
  __syncthreads();

  for (int t=0;t<Tn;t++){
    build_pred(xh, pred, hS, tid);
    __syncthreads();
    gemm_gates<192>(wc + 3*131072, bias + 3*G4, xh, gatesP, tid);
    __syncthreads();
    activate(gatesP, hS, cS, tid);
    __syncthreads();

    build_mid(xh, hS, hS + BR*Hn, tid);
    __syncthreads();
    gemm_gates<256>(wc + 4*131072, bias + 4*G4, xh, gatesP, tid);
    __syncthreads();
    activate(gatesP, hS + BR*Hn, cS + BR*Hn, tid);
    __syncthreads();

    build_mid(xh, hS + BR*Hn, hS + 2*BR*Hn, tid);
    __syncthreads();
    gemm_gates<256>(wc + 5*131072, bias + 5*G4, xh, gatesP, tid);
    __syncthreads();
    activate(gatesP, hS + 2*BR*Hn, cS + 2*BR*Hn, tid);
    __syncthreads();

    proj_out(hS + 2*BR*Hn, fwt, fbw, pred, out, b0, t, tid);
    __syncthreads();
  }
}

extern "C" void kernel_launch(void* const* d_in, const int* in_sizes, int n_in,
                              void* d_out, int out_size, void* d_ws, size_t ws_size,
                              hipStream_t stream)
{
  (void)in_sizes; (void)n_in; (void)out_size; (void)ws_size;
  const float* src = (const float*)d_in[0];
  WP p;
  for (int l=0;l<3;l++){
    p.W[l]    = (const float*)d_in[1  + 3*l];
    p.U[l]    = (const float*)d_in[2  + 3*l];
    p.Bb[l]   = (const float*)d_in[3  + 3*l];
    p.W[3+l]  = (const float*)d_in[10 + 3*l];
    p.U[3+l]  = (const float*)d_in[11 + 3*l];
    p.Bb[3+l] = (const float*)d_in[12 + 3*l];
  }
  p.fW = (const float*)d_in[19];
  p.fb = (const float*)d_in[20];

  // ws layout (fp32): wc[786432] | bias[3072] | fwt[8192] | fbw[64]
  float* wc   = (float*)d_ws;
  float* bias = wc + 6*131072;
  float* fwt  = bias + 6*512;
  float* fbw  = fwt + 8192;

  prep_kernel<<<(PREP_TOTAL + 255)/256, 256, 0, stream>>>(p, wc, bias, fwt, fbw);
  lstm_kernel<<<NWG, NTH, 0, stream>>>(src, wc, bias, fwt, fbw, (float*)d_out);
}